// Round 1
// baseline (437.596 us; speedup 1.0000x reference)
//
#include <hip/hip_runtime.h>

#define IMG_H 256
#define IMG_W 256
#define ROWS_PER_WAVE 64
#define STRIPS 4   // IMG_H / ROWS_PER_WAVE
#define N_IMG 1024 // 16*64

__device__ __forceinline__ float4 fmax4(const float4 a, const float4 b) {
    return make_float4(fmaxf(a.x, b.x), fmaxf(a.y, b.y), fmaxf(a.z, b.z), fmaxf(a.w, b.w));
}

// Fused hex maxpool: out[h][w] = max over hex window (19 taps), OOB -> 0.0
// w even: col w rows h-2..h+2 ; cols w+-1 rows h-2..h+1 ; cols w+-2 rows h-1..h+1
// w odd : col w rows h-2..h+2 ; cols w+-1 rows h-1..h+2 ; cols w+-2 rows h-1..h+1
__global__ __launch_bounds__(256) void hex_maxpool_kernel(const float* __restrict__ in,
                                                          float* __restrict__ out) {
    const int lane  = threadIdx.x & 63;
    const int wave  = threadIdx.x >> 6;
    const int gw    = blockIdx.x * 4 + wave;      // global wave id, 0..4095
    const int img   = gw >> 2;                    // 0..1023
    const int strip = gw & 3;                     // 0..3
    const int h0    = strip * ROWS_PER_WAVE;
    const int col   = lane * 4;                   // 64 lanes * 4 = 256 = full row

    const float* p = in  + (size_t)img * (IMG_H * IMG_W);
    float*       q = out + (size_t)img * (IMG_H * IMG_W);

    auto load_row = [&](int r) -> float4 {
        if ((unsigned)r < (unsigned)IMG_H) {
            return *reinterpret_cast<const float4*>(p + r * IMG_W + col);
        }
        return make_float4(0.f, 0.f, 0.f, 0.f);
    };

    // sliding window rows h-2 .. h+2 for h = h0
    float4 w0 = load_row(h0 - 2);
    float4 w1 = load_row(h0 - 1);
    float4 w2 = load_row(h0);
    float4 w3 = load_row(h0 + 1);
    float4 w4 = load_row(h0 + 2);

    for (int h = h0; h < h0 + ROWS_PER_WAVE; ++h) {
        // prefetch next row (row h+3, needed for next iteration)
        const float4 wn = load_row(h + 3);

        // per-column vertical aggregates (4 columns per lane)
        const float4 m3 = fmax4(fmax4(w1, w2), w3); // rows h-1..h+1
        const float4 bu = fmax4(m3, w0);            // rows h-2..h+1
        const float4 bd = fmax4(m3, w4);            // rows h-1..h+2
        const float4 a5 = fmax4(bu, w4);            // rows h-2..h+2

        // cross-lane neighbor aggregates
        float Lbuw = __shfl_up(bu.w, 1);
        float Lm3z = __shfl_up(m3.z, 1);
        float Lm3w = __shfl_up(m3.w, 1);
        float Rbdx = __shfl_down(bd.x, 1);
        float Rm3x = __shfl_down(m3.x, 1);
        float Rm3y = __shfl_down(m3.y, 1);
        if (lane == 0)  { Lbuw = 0.f; Lm3z = 0.f; Lm3w = 0.f; }  // cols -1,-2 are pad(0)
        if (lane == 63) { Rbdx = 0.f; Rm3x = 0.f; Rm3y = 0.f; }  // cols 256,257 are pad(0)

        float4 o;
        // col+0 (even): A[0], Bup[-1], Bup[1], m3[-2], m3[2]
        o.x = fmaxf(fmaxf(fmaxf(a5.x, Lbuw), bu.y), fmaxf(Lm3z, m3.z));
        // col+1 (odd):  A[1], Bdn[0], Bdn[2], m3[-1], m3[3]
        o.y = fmaxf(fmaxf(fmaxf(a5.y, bd.x), bd.z), fmaxf(Lm3w, m3.w));
        // col+2 (even): A[2], Bup[1], Bup[3], m3[0], m3[4]
        o.z = fmaxf(fmaxf(fmaxf(a5.z, bu.y), bu.w), fmaxf(m3.x, Rm3x));
        // col+3 (odd):  A[3], Bdn[2], Bdn[4], m3[1], m3[5]
        o.w = fmaxf(fmaxf(fmaxf(a5.w, bd.z), Rbdx), fmaxf(m3.y, Rm3y));

        *reinterpret_cast<float4*>(q + h * IMG_W + col) = o;

        // slide window
        w0 = w1; w1 = w2; w2 = w3; w3 = w4; w4 = wn;
    }
}

extern "C" void kernel_launch(void* const* d_in, const int* in_sizes, int n_in,
                              void* d_out, int out_size, void* d_ws, size_t ws_size,
                              hipStream_t stream) {
    (void)in_sizes; (void)n_in; (void)d_ws; (void)ws_size; (void)out_size;
    const float* in = (const float*)d_in[0];
    float* out = (float*)d_out;
    // grid: 1024 images * 4 strips = 4096 waves = 1024 blocks of 4 waves
    hex_maxpool_kernel<<<N_IMG * STRIPS / 4, 256, 0, stream>>>(in, out);
}